// Round 8
// baseline (2072.031 us; speedup 1.0000x reference)
//
#include <hip/hip_runtime.h>
#include <math.h>

#define BB 256
#define TT 2048
#define HH 64

typedef _Float16 half2v __attribute__((ext_vector_type(2)));
typedef __fp16  fp16v2 __attribute__((ext_vector_type(2)));
union H2I { half2v h; unsigned int i; };

#if __has_builtin(__builtin_amdgcn_rcpf)
__device__ __forceinline__ float fast_rcp(float v) { return __builtin_amdgcn_rcpf(v); }
#else
__device__ __forceinline__ float fast_rcp(float v) { return 1.0f / v; }
#endif
#if __has_builtin(__builtin_amdgcn_rsqf)
__device__ __forceinline__ float fast_rsq(float v) { return __builtin_amdgcn_rsqf(v); }
#else
__device__ __forceinline__ float fast_rsq(float v) { return rsqrtf(v); }
#endif

__device__ __forceinline__ float tanh_fast(float v) {
    // tanh(x) = 1 - 2/(e^{2x}+1); saturates correctly at +/-inf
    float e = __expf(2.0f * v);
    return fmaf(-2.0f, fast_rcp(e + 1.0f), 1.0f);
}

__device__ __forceinline__ float sigmoid_fast(float v) {
    return fast_rcp(1.0f + __expf(-v));
}

__device__ __forceinline__ float fdot2(half2v a, half2v b, float c) {
    return __builtin_amdgcn_fdot2(a, b, c, false);
}

__device__ __forceinline__ half2v pack_pair(float a, float b) {
    fp16v2 r = __builtin_amdgcn_cvt_pkrtz(a, b);
    return __builtin_bit_cast(half2v, r);
}

// force a value to live in a register (defeat load-rematerialization)
__device__ __forceinline__ void pin_h2(half2v& v) {
    H2I u; u.h = v;
    asm volatile("" : "+v"(u.i));
    v = u.h;
}

// neighbor value within a quad: lane j gets lane j^1 (DPP quad_perm [1,0,3,2])
__device__ __forceinline__ float dpp_neighbor(float v) {
    return __int_as_float(__builtin_amdgcn_mov_dpp(__float_as_int(v), 0xB1, 0xf, 0xf, true));
}

__device__ __forceinline__ half2v h2_from_u32(unsigned int w) {
    H2I u; u.i = w;
    return u.h;
}

__global__ __launch_bounds__(64, 1)
void pgjanet_kernel(const float* __restrict__ x,
                    const float* __restrict__ h0,
                    const float* __restrict__ Wa,  const float* __restrict__ ba,
                    const float* __restrict__ Wp1, const float* __restrict__ bp1,
                    const float* __restrict__ Wp2, const float* __restrict__ bp2,
                    const float* __restrict__ Wf,  const float* __restrict__ bf,
                    const float* __restrict__ Wg,  const float* __restrict__ bg,
                    const float* __restrict__ Wo,  const float* __restrict__ bo,
                    float* __restrict__ out)
{
    const int b = blockIdx.x;
    const int j = threadIdx.x;   // 0..63 : hidden index, single wave per block

    __shared__ float4 xt[TT];                         // 32 KB: (amp, cos, sin, 0) per t
    __shared__ float  hbuf[64][HH + 1];               // 16.6 KB h ring; stride 65 -> conflict-free
    __shared__ float  woLDS[2 * HH];                  // 0.5 KB
    __shared__ __align__(16) unsigned int hpk[64];    // packed h pairs; [0:32) real, [32:64) odd-lane dump
    __shared__ __align__(16) unsigned int upk[64];    // packed u pairs

    // ---- x-table: precompute amp/cos/sin once (removes per-step rsq/cndmask) ----
    for (int t = j; t < TT; t += 64) {
        float2 xi = reinterpret_cast<const float2*>(x)[(size_t)b * TT + t];
        float r2 = xi.x * xi.x + xi.y * xi.y;
        float rq = fast_rsq(r2);
        bool ok = r2 > 0.f;
        xt[t] = make_float4(ok ? r2 * rq : 0.f,    // amp
                            ok ? xi.x * rq : 1.f,  // cos(atan2(q,i))
                            ok ? xi.y * rq : 0.f,  // sin
                            0.f);
    }
    for (int i = j; i < 2 * HH; i += 64) woLDS[i] = Wo[i];

    // ---- all weights in-register (AGPR parking is fine on gfx950 unified file) ----
    half2v w5[5][32], wfu[32], wgu[32];
    {
        const float* Wsrc[5] = {Wa, Wp1, Wp2, Wf, Wg};
        const int    ldv[5]  = {HH + 1, HH + 1, HH + 1, 2 * HH, 2 * HH};
#pragma unroll
        for (int g = 0; g < 5; ++g) {
            const float* r = Wsrc[g] + (size_t)j * ldv[g];
#pragma unroll
            for (int m = 0; m < 32; ++m) w5[g][m] = pack_pair(r[2 * m], r[2 * m + 1]);
        }
        const float* rf = Wf + (size_t)j * (2 * HH) + HH;
        const float* rg = Wg + (size_t)j * (2 * HH) + HH;
#pragma unroll
        for (int m = 0; m < 32; ++m) {
            wfu[m] = pack_pair(rf[2 * m], rf[2 * m + 1]);
            wgu[m] = pack_pair(rg[2 * m], rg[2 * m + 1]);
        }
#pragma unroll
        for (int g = 0; g < 5; ++g)
#pragma unroll
            for (int m = 0; m < 32; ++m) pin_h2(w5[g][m]);
#pragma unroll
        for (int m = 0; m < 32; ++m) { pin_h2(wfu[m]); pin_h2(wgu[m]); }
    }

    const float waX  = Wa [j * (HH + 1) + HH];
    const float wp1X = Wp1[j * (HH + 1) + HH];
    const float wp2X = Wp2[j * (HH + 1) + HH];
    const float ba_r = ba[j], bp1_r = bp1[j], bp2_r = bp2[j];
    const float bf_r = bf[j], bg_r = bg[j];
    const float bo0  = bo[0], bo1 = bo[1];

    // broadcast write slot: even lanes -> [0:32) (real), odd lanes -> [32:64) (dump).
    // 2 lanes/bank on the write -> free; no exec-mask manipulation needed.
    const int bslot = ((j & 1) << 5) + (j >> 1);

    float  h  = h0[b * HH + j];
    float* yp = out + (size_t)b * (TT * 2);

    __syncthreads();   // single wave: near-free; orders staging

    float4 xv = xt[0];

    for (int t = 0; t < TT; ++t) {
        // prefetch next step's x scalars (uniform ds_read_b128; used next iter)
        const int tn = (t + 1 < TT) ? (t + 1) : t;
        float4 xv_n = xt[tn];

        // ---- h broadcast via LDS: pack pair, unconditional write, read b128 ----
        {
            float hn = dpp_neighbor(h);
            H2I hp; hp.h = pack_pair(h, hn);   // even lane j: (h_j, h_{j+1})
            hpk[bslot] = hp.i;
        }
        uint4 hw[8];
#pragma unroll
        for (int i = 0; i < 8; ++i) hw[i] = reinterpret_cast<const uint4*>(hpk)[i];

        // ---- phase A: 5 h-matvecs, 10 accumulator chains (16-deep) ----
        float A0 = fmaf(xv.x, waX,  ba_r);
        float A1 = fmaf(xv.y, wp1X, bp1_r);
        float A2 = fmaf(xv.z, wp2X, bp2_r);
        float A3 = bf_r;
        float A4 = bg_r;
        float B0 = 0.f, B1 = 0.f, B2 = 0.f, B3 = 0.f, B4 = 0.f;
#pragma unroll
        for (int i = 0; i < 4; ++i) {
#pragma unroll
            for (int q = 0; q < 4; ++q) {
                const int m  = 4 * i + q;          // 0..15
                const int m2 = m + 16;             // 16..31
                half2v sA = h2_from_u32((&hw[i].x)[q]);
                half2v sB = h2_from_u32((&hw[i + 4].x)[q]);
                A0 = fdot2(sA, w5[0][m],  A0);
                A1 = fdot2(sA, w5[1][m],  A1);
                A2 = fdot2(sA, w5[2][m],  A2);
                A3 = fdot2(sA, w5[3][m],  A3);
                A4 = fdot2(sA, w5[4][m],  A4);
                B0 = fdot2(sB, w5[0][m2], B0);
                B1 = fdot2(sB, w5[1][m2], B1);
                B2 = fdot2(sB, w5[2][m2], B2);
                B3 = fdot2(sB, w5[3][m2], B3);
                B4 = fdot2(sB, w5[4][m2], B4);
            }
        }
        float acc0 = A0 + B0;
        float acc1 = A1 + B1;
        float acc2 = A2 + B2;
        float acc3 = A3 + B3;
        float acc4 = A4 + B4;

        float av = tanh_fast(acc0);
        float p1 = tanh_fast(acc1);
        float p2 = tanh_fast(acc2);
        // u = a(1-a) * p1(1-p1) * p2(1-p2)
        float u = fmaf(-av, av, av) * fmaf(-p1, p1, p1) * fmaf(-p2, p2, p2);

        // ---- u broadcast via LDS (same pattern) ----
        {
            float un = dpp_neighbor(u);
            H2I up; up.h = pack_pair(u, un);
            upk[bslot] = up.i;
        }
        uint4 uw[8];
#pragma unroll
        for (int i = 0; i < 8; ++i) uw[i] = reinterpret_cast<const uint4*>(upk)[i];

        // ---- phase C: f,g u-dots, 8 chains (8-deep) ----
        float f0 = acc3, f1 = 0.f, f2 = 0.f, f3 = 0.f;
        float g0 = acc4, g1 = 0.f, g2 = 0.f, g3 = 0.f;
#pragma unroll
        for (int i = 0; i < 2; ++i) {
#pragma unroll
            for (int q = 0; q < 4; ++q) {
                const int m0 = 4 * i + q;          // 0..7
                const int m1 = m0 + 8;             // 8..15
                const int m2 = m0 + 16;            // 16..23
                const int m3 = m0 + 24;            // 24..31
                half2v s0 = h2_from_u32((&uw[i].x)[q]);
                half2v s1 = h2_from_u32((&uw[i + 2].x)[q]);
                half2v s2 = h2_from_u32((&uw[i + 4].x)[q]);
                half2v s3 = h2_from_u32((&uw[i + 6].x)[q]);
                f0 = fdot2(s0, wfu[m0], f0);
                f1 = fdot2(s1, wfu[m1], f1);
                f2 = fdot2(s2, wfu[m2], f2);
                f3 = fdot2(s3, wfu[m3], f3);
                g0 = fdot2(s0, wgu[m0], g0);
                g1 = fdot2(s1, wgu[m1], g1);
                g2 = fdot2(s2, wgu[m2], g2);
                g3 = fdot2(s3, wgu[m3], g3);
            }
        }
        float f = sigmoid_fast((f0 + f1) + (f2 + f3));
        float g = tanh_fast((g0 + g1) + (g2 + g3));
        h = fmaf(f, h - g, g);   // f*h + (1-f)*g

        // y deferred: 1 conflict-free ds_write per step into the ring
        hbuf[t & 63][j] = h;

        if ((t & 63) == 63) {
            // flush: lane L computes y(t-63+L) in f32; woLDS reads broadcast,
            // hbuf reads stride 65 words -> conflict-free
            float y0 = bo0, y1 = bo1;
#pragma unroll 4
            for (int k = 0; k < HH; ++k) {
                float hv = hbuf[j][k];
                y0 = fmaf(hv, woLDS[k],      y0);
                y1 = fmaf(hv, woLDS[HH + k], y1);
            }
            reinterpret_cast<float2*>(yp)[(t - 63) + j] = make_float2(y0, y1);
        }

        xv = xv_n;
    }
}

extern "C" void kernel_launch(void* const* d_in, const int* in_sizes, int n_in,
                              void* d_out, int out_size, void* d_ws, size_t ws_size,
                              hipStream_t stream) {
    const float* x   = (const float*)d_in[0];
    const float* h0  = (const float*)d_in[1];
    const float* Wa  = (const float*)d_in[2];
    const float* ba  = (const float*)d_in[3];
    const float* Wp1 = (const float*)d_in[4];
    const float* bp1 = (const float*)d_in[5];
    const float* Wp2 = (const float*)d_in[6];
    const float* bp2 = (const float*)d_in[7];
    const float* Wf  = (const float*)d_in[8];
    const float* bf  = (const float*)d_in[9];
    const float* Wg  = (const float*)d_in[10];
    const float* bg  = (const float*)d_in[11];
    const float* Wo  = (const float*)d_in[12];
    const float* bo  = (const float*)d_in[13];
    float* out = (float*)d_out;

    pgjanet_kernel<<<dim3(BB), dim3(64), 0, stream>>>(
        x, h0, Wa, ba, Wp1, bp1, Wp2, bp2, Wf, bf, Wg, bg, Wo, bo, out);
}

// Round 10
// 1711.245 us; speedup vs baseline: 1.2108x; 1.2108x over previous
//
#include <hip/hip_runtime.h>
#include <math.h>

#define BB 256
#define TT 2048
#define HH 64

typedef _Float16 half2v __attribute__((ext_vector_type(2)));
typedef __fp16  fp16v2 __attribute__((ext_vector_type(2)));
typedef _Float16 half8  __attribute__((ext_vector_type(8)));
typedef float    f32x4  __attribute__((ext_vector_type(4)));
union H2I { half2v h; unsigned int i; };
union F8  { half8 h; uint4 u; };

#if __has_builtin(__builtin_amdgcn_rcpf)
__device__ __forceinline__ float fast_rcp(float v) { return __builtin_amdgcn_rcpf(v); }
#else
__device__ __forceinline__ float fast_rcp(float v) { return 1.0f / v; }
#endif
#if __has_builtin(__builtin_amdgcn_rsqf)
__device__ __forceinline__ float fast_rsq(float v) { return __builtin_amdgcn_rsqf(v); }
#else
__device__ __forceinline__ float fast_rsq(float v) { return rsqrtf(v); }
#endif

__device__ __forceinline__ float tanh_fast(float v) {
    float e = __expf(2.0f * v);
    return fmaf(-2.0f, fast_rcp(e + 1.0f), 1.0f);
}
__device__ __forceinline__ float sigmoid_fast(float v) {
    return fast_rcp(1.0f + __expf(-v));
}
__device__ __forceinline__ float fdot2(half2v a, half2v b, float c) {
    return __builtin_amdgcn_fdot2(a, b, c, false);
}
__device__ __forceinline__ half2v pack_pair(float a, float b) {
    fp16v2 r = __builtin_amdgcn_cvt_pkrtz(a, b);
    return __builtin_bit_cast(half2v, r);
}
__device__ __forceinline__ unsigned pack_u32(float a, float b) {
    fp16v2 r = __builtin_amdgcn_cvt_pkrtz(a, b);
    return __builtin_bit_cast(unsigned, r);
}
__device__ __forceinline__ void pin_h2(half2v& v) {
    H2I u; u.h = v;
    asm volatile("" : "+v"(u.i));
    v = u.h;
}
__device__ __forceinline__ void pin_f8(half8& v) {
    F8 f; f.h = v;
    asm volatile("" : "+v"(f.u.x), "+v"(f.u.y), "+v"(f.u.z), "+v"(f.u.w));
    v = f.h;
}
// broadcast packed f16x2 from a wave-uniform (even) lane -> SGPR operand for dots
__device__ __forceinline__ half2v bcast_pair(half2v v, int lane) {
    H2I u; u.h = v;
    H2I w; w.i = __builtin_amdgcn_readlane(u.i, lane);
    return w.h;
}
// neighbor within quad: lane j gets lane j^1
__device__ __forceinline__ float dpp_neighbor(float v) {
    return __int_as_float(__builtin_amdgcn_mov_dpp(__float_as_int(v), 0xB1, 0xf, 0xf, true));
}
// build one B/A fragment (8 consecutive k-elements of one row/col) from f32 memory
__device__ __forceinline__ half8 make_frag(const float* p) {
    F8 f;
    f.u.x = pack_u32(p[0], p[1]);
    f.u.y = pack_u32(p[2], p[3]);
    f.u.z = pack_u32(p[4], p[5]);
    f.u.w = pack_u32(p[6], p[7]);
    return f.h;
}

__global__ __launch_bounds__(64, 1)
void pgjanet_kernel(const float* __restrict__ x,
                    const float* __restrict__ h0,
                    const float* __restrict__ Wa,  const float* __restrict__ ba,
                    const float* __restrict__ Wp1, const float* __restrict__ bp1,
                    const float* __restrict__ Wp2, const float* __restrict__ bp2,
                    const float* __restrict__ Wf,  const float* __restrict__ bf,
                    const float* __restrict__ Wg,  const float* __restrict__ bg,
                    const float* __restrict__ Wo,  const float* __restrict__ bo,
                    float* __restrict__ out)
{
    const int b = blockIdx.x;
    const int j = threadIdx.x;        // 0..63 : hidden index, single wave
    const int c   = j & 15;           // col within 16-wide mfma tile
    const int grp = j >> 4;           // k-group for fragments / tile-select

    __shared__ float4 xt[TT];                       // 32 KB (amp, cos, sin, 0)
    __shared__ float  hbuf[64][HH + 1];             // h ring, stride 65
    __shared__ float  woLDS[2 * HH];
    __shared__ __align__(16) unsigned int hpk[32];  // packed h pairs
    __shared__ __align__(16) unsigned int upk[32];  // packed u pairs

    // ---- x-table ----
    for (int t = j; t < TT; t += 64) {
        float2 xi = reinterpret_cast<const float2*>(x)[(size_t)b * TT + t];
        float r2 = xi.x * xi.x + xi.y * xi.y;
        float rq = fast_rsq(r2);
        bool ok = r2 > 0.f;
        xt[t] = make_float4(ok ? r2 * rq : 0.f, ok ? xi.x * rq : 1.f,
                            ok ? xi.y * rq : 0.f, 0.f);
    }
    for (int i = j; i < 2 * HH; i += 64) woLDS[i] = Wo[i];

    // ---- MFMA B-fragments: W^T tiles. B[k][col]=W[16*tau+c][k], k=32*kt+grp*8+e ----
    half8 WB[3][4][2];   // gates a,p1,p2 (h-part, ld 65)
    half8 UBf[4][2];     // Wf u-part (cols 64..127, ld 128)
    {
        const float* WsrcA[3] = {Wa, Wp1, Wp2};
#pragma unroll
        for (int g = 0; g < 3; ++g)
#pragma unroll
            for (int tau = 0; tau < 4; ++tau)
#pragma unroll
                for (int kt = 0; kt < 2; ++kt)
                    WB[g][tau][kt] = make_frag(WsrcA[g] + (size_t)(16 * tau + c) * (HH + 1) + 32 * kt + grp * 8);
#pragma unroll
        for (int tau = 0; tau < 4; ++tau)
#pragma unroll
            for (int kt = 0; kt < 2; ++kt)
                UBf[tau][kt] = make_frag(Wf + (size_t)(16 * tau + c) * (2 * HH) + HH + 32 * kt + grp * 8);
#pragma unroll
        for (int g = 0; g < 3; ++g)
#pragma unroll
            for (int tau = 0; tau < 4; ++tau)
#pragma unroll
                for (int kt = 0; kt < 2; ++kt) pin_f8(WB[g][tau][kt]);
#pragma unroll
        for (int tau = 0; tau < 4; ++tau)
#pragma unroll
            for (int kt = 0; kt < 2; ++kt) pin_f8(UBf[tau][kt]);
    }

    // ---- VALU dot weights: fh, gh (h-parts) and Wg u-part ----
    half2v wfh[32], wgh[32], wgu[32];
    {
        const float* rf = Wf + (size_t)j * (2 * HH);
        const float* rg = Wg + (size_t)j * (2 * HH);
#pragma unroll
        for (int m = 0; m < 32; ++m) {
            wfh[m] = pack_pair(rf[2 * m], rf[2 * m + 1]);
            wgh[m] = pack_pair(rg[2 * m], rg[2 * m + 1]);
            wgu[m] = pack_pair(rg[HH + 2 * m], rg[HH + 2 * m + 1]);
        }
#pragma unroll
        for (int m = 0; m < 32; ++m) { pin_h2(wfh[m]); pin_h2(wgh[m]); pin_h2(wgu[m]); }
    }

    const float waX  = Wa [j * (HH + 1) + HH];
    const float wp1X = Wp1[j * (HH + 1) + HH];
    const float wp2X = Wp2[j * (HH + 1) + HH];
    const float ba_r = ba[j], bp1_r = bp1[j], bp2_r = bp2[j];
    const float bf_r = bf[j], bg_r = bg[j];
    const float bo0  = bo[0], bo1 = bo[1];

    float  h  = h0[b * HH + j];
    float* yp = out + (size_t)b * (TT * 2);

    __syncthreads();

    const bool b4 = (j & 16) != 0, b5 = (j & 32) != 0;
    const f32x4 zz = {0.f, 0.f, 0.f, 0.f};
    float4 xv = xt[0];

    for (int t = 0; t < TT; ++t) {
        const int tn = (t + 1 < TT) ? (t + 1) : t;
        float4 xv_n = xt[tn];

        // ---- h -> LDS marshal (issued early; dot work below covers latency) ----
        float hn = dpp_neighbor(h);
        half2v hp = pack_pair(h, hn);
        {
            H2I w_; w_.h = hp;
            if ((j & 1) == 0) hpk[j >> 1] = w_.i;
        }
        F8 a0u, a1u;
        a0u.u = *reinterpret_cast<const uint4*>(&hpk[grp * 4]);        // k-tile 0
        a1u.u = *reinterpret_cast<const uint4*>(&hpk[16 + grp * 4]);   // k-tile 1

        // ---- VALU: fh, gh dots (readlane broadcast, 4 chains) ----
        float F0 = bf_r, F1 = 0.f, G0 = bg_r, G1 = 0.f;
#pragma unroll
        for (int m = 0; m < 16; ++m) {
            half2v s0 = bcast_pair(hp, 2 * m);
            half2v s1 = bcast_pair(hp, 2 * (m + 16));
            F0 = fdot2(s0, wfh[m],      F0);
            F1 = fdot2(s1, wfh[m + 16], F1);
            G0 = fdot2(s0, wgh[m],      G0);
            G1 = fdot2(s1, wgh[m + 16], G1);
        }
        float accF = F0 + F1;   // bf + Wf_h . h
        float accG = G0 + G1;   // bg + Wg_h . h

        // ---- MFMA: a, p1, p2 (24 mfma, independent of the dots above) ----
        half8 hA0 = a0u.h, hA1 = a1u.h;
        f32x4 accA[3][4];
#pragma unroll
        for (int g = 0; g < 3; ++g)
#pragma unroll
            for (int tau = 0; tau < 4; ++tau) {
                accA[g][tau] = __builtin_amdgcn_mfma_f32_16x16x32_f16(hA0, WB[g][tau][0], zz, 0, 0, 0);
                accA[g][tau] = __builtin_amdgcn_mfma_f32_16x16x32_f16(hA1, WB[g][tau][1], accA[g][tau], 0, 0, 0);
            }

        // ---- tile-select (3 cndmask/gate; rows are duplicates so reg0 valid) ----
        float pre[3];
#pragma unroll
        for (int g = 0; g < 3; ++g) {
            float s01 = b4 ? accA[g][1][0] : accA[g][0][0];
            float s23 = b4 ? accA[g][3][0] : accA[g][2][0];
            pre[g] = b5 ? s23 : s01;
        }
        float av = tanh_fast(pre[0] + fmaf(xv.x, waX,  ba_r));
        float p1 = tanh_fast(pre[1] + fmaf(xv.y, wp1X, bp1_r));
        float p2 = tanh_fast(pre[2] + fmaf(xv.z, wp2X, bp2_r));
        float u = fmaf(-av, av, av) * fmaf(-p1, p1, p1) * fmaf(-p2, p2, p2);

        // ---- u -> LDS marshal (early), g-dots cover latency ----
        float un = dpp_neighbor(u);
        half2v up = pack_pair(u, un);
        {
            H2I w_; w_.h = up;
            if ((j & 1) == 0) upk[j >> 1] = w_.i;
        }
        F8 u0u, u1u;
        u0u.u = *reinterpret_cast<const uint4*>(&upk[grp * 4]);
        u1u.u = *reinterpret_cast<const uint4*>(&upk[16 + grp * 4]);

        // ---- VALU: g u-dots ----
        float Gu0 = accG, Gu1 = 0.f;
#pragma unroll
        for (int m = 0; m < 16; ++m) {
            half2v s0 = bcast_pair(up, 2 * m);
            half2v s1 = bcast_pair(up, 2 * (m + 16));
            Gu0 = fdot2(s0, wgu[m],      Gu0);
            Gu1 = fdot2(s1, wgu[m + 16], Gu1);
        }

        // ---- MFMA: f u-part (8 mfma) ----
        half8 uA0 = u0u.h, uA1 = u1u.h;
        f32x4 accCf[4];
#pragma unroll
        for (int tau = 0; tau < 4; ++tau) {
            accCf[tau] = __builtin_amdgcn_mfma_f32_16x16x32_f16(uA0, UBf[tau][0], zz, 0, 0, 0);
            accCf[tau] = __builtin_amdgcn_mfma_f32_16x16x32_f16(uA1, UBf[tau][1], accCf[tau], 0, 0, 0);
        }
        float fs01 = b4 ? accCf[1][0] : accCf[0][0];
        float fs23 = b4 ? accCf[3][0] : accCf[2][0];
        float fu   = b5 ? fs23 : fs01;

        float f = sigmoid_fast(accF + fu);
        float g = tanh_fast(Gu0 + Gu1);
        h = fmaf(f, h - g, g);   // f*h + (1-f)*g

        hbuf[t & 63][j] = h;

        if ((t & 63) == 63) {
            float y0 = bo0, y1 = bo1;
#pragma unroll 4
            for (int k = 0; k < HH; ++k) {
                float hv = hbuf[j][k];
                y0 = fmaf(hv, woLDS[k],      y0);
                y1 = fmaf(hv, woLDS[HH + k], y1);
            }
            reinterpret_cast<float2*>(yp)[(t - 63) + j] = make_float2(y0, y1);
        }

        xv = xv_n;
    }
}

extern "C" void kernel_launch(void* const* d_in, const int* in_sizes, int n_in,
                              void* d_out, int out_size, void* d_ws, size_t ws_size,
                              hipStream_t stream) {
    const float* x   = (const float*)d_in[0];
    const float* h0  = (const float*)d_in[1];
    const float* Wa  = (const float*)d_in[2];
    const float* ba  = (const float*)d_in[3];
    const float* Wp1 = (const float*)d_in[4];
    const float* bp1 = (const float*)d_in[5];
    const float* Wp2 = (const float*)d_in[6];
    const float* bp2 = (const float*)d_in[7];
    const float* Wf  = (const float*)d_in[8];
    const float* bf  = (const float*)d_in[9];
    const float* Wg  = (const float*)d_in[10];
    const float* bg  = (const float*)d_in[11];
    const float* Wo  = (const float*)d_in[12];
    const float* bo  = (const float*)d_in[13];
    float* out = (float*)d_out;

    pgjanet_kernel<<<dim3(BB), dim3(64), 0, stream>>>(
        x, h0, Wa, ba, Wp1, bp1, Wp2, bp2, Wf, bf, Wg, bg, Wo, bo, out);
}

// Round 11
// 1505.054 us; speedup vs baseline: 1.3767x; 1.1370x over previous
//
#include <hip/hip_runtime.h>
#include <math.h>

#define BB 256
#define TT 2048
#define HH 64

typedef _Float16 half2v __attribute__((ext_vector_type(2)));
typedef __fp16  fp16v2 __attribute__((ext_vector_type(2)));
typedef _Float16 half8  __attribute__((ext_vector_type(8)));
typedef float    f32x4  __attribute__((ext_vector_type(4)));
union H2I { half2v h; unsigned int i; };
union F8  { half8 h; uint4 u; };

#if __has_builtin(__builtin_amdgcn_rcpf)
__device__ __forceinline__ float fast_rcp(float v) { return __builtin_amdgcn_rcpf(v); }
#else
__device__ __forceinline__ float fast_rcp(float v) { return 1.0f / v; }
#endif
#if __has_builtin(__builtin_amdgcn_rsqf)
__device__ __forceinline__ float fast_rsq(float v) { return __builtin_amdgcn_rsqf(v); }
#else
__device__ __forceinline__ float fast_rsq(float v) { return rsqrtf(v); }
#endif

__device__ __forceinline__ float tanh_fast(float v) {
    float e = __expf(2.0f * v);
    return fmaf(-2.0f, fast_rcp(e + 1.0f), 1.0f);
}
__device__ __forceinline__ float sigmoid_fast(float v) {
    return fast_rcp(1.0f + __expf(-v));
}
__device__ __forceinline__ half2v pack_pair(float a, float b) {
    fp16v2 r = __builtin_amdgcn_cvt_pkrtz(a, b);
    return __builtin_bit_cast(half2v, r);
}
__device__ __forceinline__ unsigned pack_u32(float a, float b) {
    fp16v2 r = __builtin_amdgcn_cvt_pkrtz(a, b);
    return __builtin_bit_cast(unsigned, r);
}
__device__ __forceinline__ void pin_f8(half8& v) {
    F8 f; f.h = v;
    asm volatile("" : "+v"(f.u.x), "+v"(f.u.y), "+v"(f.u.z), "+v"(f.u.w));
    v = f.h;
}
// neighbor within quad: lane j gets lane j^1
__device__ __forceinline__ float dpp_neighbor(float v) {
    return __int_as_float(__builtin_amdgcn_mov_dpp(__float_as_int(v), 0xB1, 0xf, 0xf, true));
}
// build one B fragment (8 consecutive k-elements of one W row) from f32 memory
__device__ __forceinline__ half8 make_frag(const float* p) {
    F8 f;
    f.u.x = pack_u32(p[0], p[1]);
    f.u.y = pack_u32(p[2], p[3]);
    f.u.z = pack_u32(p[4], p[5]);
    f.u.w = pack_u32(p[6], p[7]);
    return f.h;
}

__global__ __launch_bounds__(64, 1)
void pgjanet_kernel(const float* __restrict__ x,
                    const float* __restrict__ h0,
                    const float* __restrict__ Wa,  const float* __restrict__ ba,
                    const float* __restrict__ Wp1, const float* __restrict__ bp1,
                    const float* __restrict__ Wp2, const float* __restrict__ bp2,
                    const float* __restrict__ Wf,  const float* __restrict__ bf,
                    const float* __restrict__ Wg,  const float* __restrict__ bg,
                    const float* __restrict__ Wo,  const float* __restrict__ bo,
                    float* __restrict__ out)
{
    const int b = blockIdx.x;
    const int j = threadIdx.x;        // 0..63 : hidden index, single wave
    const int c   = j & 15;           // col within 16-wide mfma tile
    const int grp = j >> 4;           // k-group for fragments / tile-select

    __shared__ float4 xt[TT];                       // 32 KB (amp, cos, sin, 0)
    __shared__ float  hbuf[64][HH + 1];             // h ring, stride 65
    __shared__ float  woLDS[2 * HH];
    __shared__ __align__(16) unsigned int hpk[32];  // packed h pairs
    __shared__ __align__(16) unsigned int upk[32];  // packed u pairs

    // ---- x-table ----
    for (int t = j; t < TT; t += 64) {
        float2 xi = reinterpret_cast<const float2*>(x)[(size_t)b * TT + t];
        float r2 = xi.x * xi.x + xi.y * xi.y;
        float rq = fast_rsq(r2);
        bool ok = r2 > 0.f;
        xt[t] = make_float4(ok ? r2 * rq : 0.f, ok ? xi.x * rq : 1.f,
                            ok ? xi.y * rq : 0.f, 0.f);
    }
    for (int i = j; i < 2 * HH; i += 64) woLDS[i] = Wo[i];

    // ---- ALL matvec weights as MFMA B-fragments (AGPR-parked; mfma reads natively) ----
    // B[k][col] = W[16*tau + c][k],  k = 32*kt + grp*8 + e   (R10-validated mapping)
    half8 WB5[5][4][2];   // h-parts: a, p1, p2, f, g
    half8 UB[2][4][2];    // u-parts: f, g  (cols 64..127 of Wf/Wg)
    {
        const float* Wsrc5[5] = {Wa, Wp1, Wp2, Wf, Wg};
        const int    ld5[5]   = {HH + 1, HH + 1, HH + 1, 2 * HH, 2 * HH};
#pragma unroll
        for (int g = 0; g < 5; ++g)
#pragma unroll
            for (int tau = 0; tau < 4; ++tau)
#pragma unroll
                for (int kt = 0; kt < 2; ++kt)
                    WB5[g][tau][kt] = make_frag(Wsrc5[g] + (size_t)(16 * tau + c) * ld5[g] + 32 * kt + grp * 8);
#pragma unroll
        for (int g2 = 0; g2 < 2; ++g2)
#pragma unroll
            for (int tau = 0; tau < 4; ++tau)
#pragma unroll
                for (int kt = 0; kt < 2; ++kt)
                    UB[g2][tau][kt] = make_frag((g2 ? Wg : Wf) + (size_t)(16 * tau + c) * (2 * HH) + HH + 32 * kt + grp * 8);
#pragma unroll
        for (int g = 0; g < 5; ++g)
#pragma unroll
            for (int tau = 0; tau < 4; ++tau)
#pragma unroll
                for (int kt = 0; kt < 2; ++kt) pin_f8(WB5[g][tau][kt]);
#pragma unroll
        for (int g2 = 0; g2 < 2; ++g2)
#pragma unroll
            for (int tau = 0; tau < 4; ++tau)
#pragma unroll
                for (int kt = 0; kt < 2; ++kt) pin_f8(UB[g2][tau][kt]);
    }

    const float waX  = Wa [j * (HH + 1) + HH];
    const float wp1X = Wp1[j * (HH + 1) + HH];
    const float wp2X = Wp2[j * (HH + 1) + HH];
    const float ba_r = ba[j], bp1_r = bp1[j], bp2_r = bp2[j];
    const float bf_r = bf[j], bg_r = bg[j];
    const float bo0  = bo[0], bo1 = bo[1];

    float  h  = h0[b * HH + j];
    float* yp = out + (size_t)b * (TT * 2);

    __syncthreads();

    const bool b4 = (j & 16) != 0, b5 = (j & 32) != 0;
    const f32x4 zz = {0.f, 0.f, 0.f, 0.f};
    float4 xv = xt[0];

    for (int t = 0; t < TT; ++t) {
        const int tn = (t + 1 < TT) ? (t + 1) : t;
        float4 xv_n = xt[tn];

        // ---- h -> LDS marshal (even lanes write packed pair; broadcast b128 reads) ----
        float hn = dpp_neighbor(h);
        half2v hp = pack_pair(h, hn);
        {
            H2I w_; w_.h = hp;
            if ((j & 1) == 0) hpk[j >> 1] = w_.i;
        }
        F8 a0u, a1u;
        a0u.u = *reinterpret_cast<const uint4*>(&hpk[grp * 4]);        // k-tile 0
        a1u.u = *reinterpret_cast<const uint4*>(&hpk[16 + grp * 4]);   // k-tile 1
        half8 hA0 = a0u.h, hA1 = a1u.h;

        // biases + x-terms early (independent of mfma results)
        float xa = fmaf(xv.x, waX,  ba_r);
        float xp1 = fmaf(xv.y, wp1X, bp1_r);
        float xp2 = fmaf(xv.z, wp2X, bp2_r);

        // ---- phase A: ALL 5 h-matvecs on MFMA (40 mfma; kt0 wave then kt1 wave) ----
        f32x4 accA[5][4];
#pragma unroll
        for (int g = 0; g < 5; ++g)
#pragma unroll
            for (int tau = 0; tau < 4; ++tau)
                accA[g][tau] = __builtin_amdgcn_mfma_f32_16x16x32_f16(hA0, WB5[g][tau][0], zz, 0, 0, 0);
#pragma unroll
        for (int g = 0; g < 5; ++g)
#pragma unroll
            for (int tau = 0; tau < 4; ++tau)
                accA[g][tau] = __builtin_amdgcn_mfma_f32_16x16x32_f16(hA1, WB5[g][tau][1], accA[g][tau], 0, 0, 0);

        // ---- tile-select a,p1,p2 (rows duplicated -> reg 0 valid) ----
        float pre[3];
#pragma unroll
        for (int g = 0; g < 3; ++g) {
            float s01 = b4 ? accA[g][1][0] : accA[g][0][0];
            float s23 = b4 ? accA[g][3][0] : accA[g][2][0];
            pre[g] = b5 ? s23 : s01;
        }
        float av = tanh_fast(pre[0] + xa);
        float p1 = tanh_fast(pre[1] + xp1);
        float p2 = tanh_fast(pre[2] + xp2);
        float u = fmaf(-av, av, av) * fmaf(-p1, p1, p1) * fmaf(-p2, p2, p2);

        // ---- u -> LDS marshal ----
        float un = dpp_neighbor(u);
        half2v up = pack_pair(u, un);
        {
            H2I w_; w_.h = up;
            if ((j & 1) == 0) upk[j >> 1] = w_.i;
        }
        F8 u0u, u1u;
        u0u.u = *reinterpret_cast<const uint4*>(&upk[grp * 4]);
        u1u.u = *reinterpret_cast<const uint4*>(&upk[16 + grp * 4]);
        half8 uA0 = u0u.h, uA1 = u1u.h;

        // ---- phase C: f,g u-parts chained onto their h-part accumulators (16 mfma) ----
#pragma unroll
        for (int g2 = 0; g2 < 2; ++g2)
#pragma unroll
            for (int tau = 0; tau < 4; ++tau)
                accA[3 + g2][tau] = __builtin_amdgcn_mfma_f32_16x16x32_f16(uA0, UB[g2][tau][0], accA[3 + g2][tau], 0, 0, 0);
#pragma unroll
        for (int g2 = 0; g2 < 2; ++g2)
#pragma unroll
            for (int tau = 0; tau < 4; ++tau)
                accA[3 + g2][tau] = __builtin_amdgcn_mfma_f32_16x16x32_f16(uA1, UB[g2][tau][1], accA[3 + g2][tau], 0, 0, 0);

        float fs01 = b4 ? accA[3][1][0] : accA[3][0][0];
        float fs23 = b4 ? accA[3][3][0] : accA[3][2][0];
        float gs01 = b4 ? accA[4][1][0] : accA[4][0][0];
        float gs23 = b4 ? accA[4][3][0] : accA[4][2][0];
        float f = sigmoid_fast((b5 ? fs23 : fs01) + bf_r);
        float g = tanh_fast((b5 ? gs23 : gs01) + bg_r);
        h = fmaf(f, h - g, g);   // f*h + (1-f)*g

        hbuf[t & 63][j] = h;

        if ((t & 63) == 63) {
            float y0 = bo0, y1 = bo1;
#pragma unroll 4
            for (int k = 0; k < HH; ++k) {
                float hv = hbuf[j][k];
                y0 = fmaf(hv, woLDS[k],      y0);
                y1 = fmaf(hv, woLDS[HH + k], y1);
            }
            reinterpret_cast<float2*>(yp)[(t - 63) + j] = make_float2(y0, y1);
        }

        xv = xv_n;
    }
}

extern "C" void kernel_launch(void* const* d_in, const int* in_sizes, int n_in,
                              void* d_out, int out_size, void* d_ws, size_t ws_size,
                              hipStream_t stream) {
    const float* x   = (const float*)d_in[0];
    const float* h0  = (const float*)d_in[1];
    const float* Wa  = (const float*)d_in[2];
    const float* ba  = (const float*)d_in[3];
    const float* Wp1 = (const float*)d_in[4];
    const float* bp1 = (const float*)d_in[5];
    const float* Wp2 = (const float*)d_in[6];
    const float* bp2 = (const float*)d_in[7];
    const float* Wf  = (const float*)d_in[8];
    const float* bf  = (const float*)d_in[9];
    const float* Wg  = (const float*)d_in[10];
    const float* bg  = (const float*)d_in[11];
    const float* Wo  = (const float*)d_in[12];
    const float* bo  = (const float*)d_in[13];
    float* out = (float*)d_out;

    pgjanet_kernel<<<dim3(BB), dim3(64), 0, stream>>>(
        x, h0, Wa, ba, Wp1, bp1, Wp2, bp2, Wf, bf, Wg, bg, Wo, bo, out);
}